// Round 1
// baseline (58.556 us; speedup 1.0000x reference)
//
#include <hip/hip_runtime.h>
#include <stdint.h>

#define B_DIM 2048
#define K_DIM 2048
#define N_PACK 4096

typedef int v4i __attribute__((ext_vector_type(4)));

__device__ __forceinline__ float fqf(float x) {
    float q = rintf(x * 32.0f);
    q = fminf(fmaxf(q, -128.0f), 127.0f);
    return q * 0.03125f;
}
__device__ __forceinline__ int q8i(float x) {
    float q = rintf(x * 32.0f);
    q = fminf(fmaxf(q, -128.0f), 127.0f);
    return (int)q;
}
__device__ __forceinline__ float fsigm(float x) {
    return __fdividef(1.0f, 1.0f + __expf(-x));
}
__device__ __forceinline__ float ftanh(float x) {
    return __fdividef(2.0f, 1.0f + __expf(-2.0f * x)) - 1.0f;
}

// One kernel quantizes everything (unchanged — at HBM roofline):
//  blocks [0, 2048)        : Xh rows  -> Xhq[m][k] int8, k<1024 from X, else h
//  blocks [2048, 6144)     : W rows   -> Wq[p][k] int8, packed p = j*4 + gate
//  block  6144             : bias     -> bqp[j*4 + gate] (fake-quantized f32)
__global__ __launch_bounds__(256) void quant_pack(
    const float* __restrict__ X, const float* __restrict__ hI,
    const float* __restrict__ W, const float* __restrict__ bias,
    int8_t* __restrict__ Xhq, int8_t* __restrict__ Wq, float* __restrict__ bqp)
{
    const int bid = blockIdx.x;
    const int t = threadIdx.x;
    if (bid < B_DIM) {
        const int m = bid;
        const int k0 = t * 8;
        const float* src = (k0 < 1024) ? (X + (size_t)m * 1024 + k0)
                                       : (hI + (size_t)m * 1024 + (k0 - 1024));
        float4 v0 = *(const float4*)src;
        float4 v1 = *(const float4*)(src + 4);
        union { int8_t c[8]; int64_t ll; } u;
        u.c[0] = (int8_t)q8i(v0.x); u.c[1] = (int8_t)q8i(v0.y);
        u.c[2] = (int8_t)q8i(v0.z); u.c[3] = (int8_t)q8i(v0.w);
        u.c[4] = (int8_t)q8i(v1.x); u.c[5] = (int8_t)q8i(v1.y);
        u.c[6] = (int8_t)q8i(v1.z); u.c[7] = (int8_t)q8i(v1.w);
        *(int64_t*)(Xhq + (size_t)m * K_DIM + k0) = u.ll;
    } else if (bid < B_DIM + N_PACK) {
        const int r = bid - B_DIM;          // original weight row (gate*1024 + j)
        const int gate = r >> 10, j = r & 1023;
        const int p = (j << 2) | gate;      // packed row
        const int k0 = t * 8;
        const float* src = W + (size_t)r * K_DIM + k0;
        float4 v0 = *(const float4*)src;
        float4 v1 = *(const float4*)(src + 4);
        union { int8_t c[8]; int64_t ll; } u;
        u.c[0] = (int8_t)q8i(v0.x); u.c[1] = (int8_t)q8i(v0.y);
        u.c[2] = (int8_t)q8i(v0.z); u.c[3] = (int8_t)q8i(v0.w);
        u.c[4] = (int8_t)q8i(v1.x); u.c[5] = (int8_t)q8i(v1.y);
        u.c[6] = (int8_t)q8i(v1.z); u.c[7] = (int8_t)q8i(v1.w);
        *(int64_t*)(Wq + (size_t)p * K_DIM + k0) = u.ll;
    } else {
        for (int idx = t; idx < N_PACK; idx += 256) {
            const int gate = idx >> 10, j = idx & 1023;
            bqp[(j << 2) | gate] = fqf(bias[idx]);
        }
    }
}

// GEMM C[2048][4096p] = Xhq @ Wq^T (int8 -> i32, exact), fused LSTM epilogue.
// R9: 8-phase-style schedule (T3+T4+T5 on top of proven T1/T2 data path).
//   BM=256, BN=128, BK=128B. Grid 256 blocks (1/CU), 512 thr (8 waves, 2Mx4N).
//   3-slot LDS pipeline (48 KB/slot: A 32K + B 16K = 144 KB): tile kt lives in
//   slot kt%3; iteration kt stages tile kt+2 into slot (kt+2)%3 = (kt-1)%3,
//   whose last reader finished before iteration kt-1's trailing barrier.
//   4 quadrant-phases per K-tile: {ds_read A-quad (+B at q0) | issue 2/2/1/1
//   staging loads | s_barrier | setprio(1) 8xMFMA setprio(0) | s_barrier}.
//   Counted vmcnt(6) ONCE per K-tile (end of iteration) = the 6 in-flight
//   loads of tile kt+2; never drained to 0 in the main loop (T4).
// XCD swizzle (T1, bijective for 256 = 8*32): xcd = b&7 owns a 4mt x 8nt
//   region -> per-XCD working set = 4 A-panels (2MB) + 8 B-panels (2MB) = L2.
// LDS chunk swizzle (T2, proven 0-conflict): LDS[r][s] holds chunk s ^ (r&7);
//   staging pre-swizzles the GLOBAL source so LDS dest stays linear (m104).
__global__ __launch_bounds__(512) void lstm_gemm(
    const int8_t* __restrict__ Xhq, const int8_t* __restrict__ Wq,
    const float* __restrict__ bqp, const float* __restrict__ cin,
    float* __restrict__ hout, float* __restrict__ cout_)
{
    __shared__ __align__(16) char raw[147456];   // 3 x (A 32K + B 16K); epilogue aliases
    const int t = threadIdx.x;          // 0..511
    const int l = t & 63;
    const int wave = t >> 6;            // 0..7
    const int wm = wave >> 2;           // 0..1  (128 m-rows each)
    const int wn = wave & 3;            // 0..3  (32 packed cols each)

    // T1: 256 blocks = 8 xcd x 32 slot; xcd -> (mt in [4a,4a+4), nt in [8b,8b+8))
    const int b = blockIdx.x;
    const int xcd = b & 7;
    const int slot = b >> 3;            // 0..31
    const int mt = ((xcd & 1) << 2) + (slot & 3);    // 0..7
    const int nt = ((xcd >> 1) << 3) + (slot >> 2);  // 0..31
    const int m0 = mt * 256;
    const int n0 = nt * 128;

    v4i acc[8][2];
    #pragma unroll
    for (int i = 0; i < 8; ++i)
        #pragma unroll
        for (int j = 0; j < 2; ++j)
            acc[i][j] = (v4i)0;

    // staging geometry: thread t covers rows {64*i + (t>>3)}, chunk-slot t&7.
    // LDS slot (r, s) holds global chunk s ^ (r&7); (64*i + r)&7 == r&7.
    const int srow = t >> 3;                      // 0..63
    const int schunk = (t & 7) ^ (srow & 7);
    const int8_t* gA = Xhq + (size_t)(m0 + srow) * K_DIM + schunk * 16;
    const int8_t* gB = Wq  + (size_t)(n0 + srow) * K_DIM + schunk * 16;

#define LDA(sb, kt, i) __builtin_amdgcn_global_load_lds( \
    (const __attribute__((address_space(1))) uint32_t*)(gA + (size_t)((i) * 64) * K_DIM + (size_t)(kt) * 128), \
    (__attribute__((address_space(3))) uint32_t*)(raw + (sb) + (i) * 8192 + t * 16), 16, 0, 0)
#define LDB(sb, kt, i) __builtin_amdgcn_global_load_lds( \
    (const __attribute__((address_space(1))) uint32_t*)(gB + (size_t)((i) * 64) * K_DIM + (size_t)(kt) * 128), \
    (__attribute__((address_space(3))) uint32_t*)(raw + (sb) + 32768 + (i) * 8192 + t * 16), 16, 0, 0)

    // Prologue: stage tile0 -> slot0, tile1 -> slot1 (6 loads each).
    LDA(0, 0, 0); LDA(0, 0, 1); LDA(0, 0, 2); LDA(0, 0, 3);
    LDB(0, 0, 0); LDB(0, 0, 1);
    LDA(49152, 1, 0); LDA(49152, 1, 1); LDA(49152, 1, 2); LDA(49152, 1, 3);
    LDB(49152, 1, 0); LDB(49152, 1, 1);
    asm volatile("s_waitcnt vmcnt(6)" ::: "memory");   // tile0 landed; tile1 in flight
    __builtin_amdgcn_s_barrier();

    const int rrow = l & 15;
    const int lx = l & 7;
    const int ccol = l >> 4;            // 0..3

    int sA = 0;                          // byte base of slot kt%3
    int sN = 2 * 49152;                  // byte base of slot (kt+2)%3
    for (int kt = 0; kt < 16; ++kt) {
        const char* As = raw + sA;
        const char* Bs = As + 32768;
        const bool st = kt < 14;         // stage tile kt+2?
        v4i bfr[2][2];
        #pragma unroll
        for (int q = 0; q < 4; ++q) {
            v4i afr[2][2];
            #pragma unroll
            for (int kk = 0; kk < 2; ++kk) {
                const int sl = ((kk * 4 + ccol) ^ lx) * 16;
                if (q == 0) {
                    #pragma unroll
                    for (int nf = 0; nf < 2; ++nf)
                        bfr[kk][nf] = *(const v4i*)(Bs + (wn * 32 + nf * 16 + rrow) * 128 + sl);
                }
                #pragma unroll
                for (int mi = 0; mi < 2; ++mi)
                    afr[kk][mi] = *(const v4i*)(As + (wm * 128 + (q * 2 + mi) * 16 + rrow) * 128 + sl);
            }
            if (st) {
                if (q == 0)      { LDA(sN, kt + 2, 0); LDA(sN, kt + 2, 1); }
                else if (q == 1) { LDA(sN, kt + 2, 2); LDA(sN, kt + 2, 3); }
                else if (q == 2) { LDB(sN, kt + 2, 0); }
                else             { LDB(sN, kt + 2, 1); }
            }
            __builtin_amdgcn_s_barrier();
            __builtin_amdgcn_s_setprio(1);
            #pragma unroll
            for (int kk = 0; kk < 2; ++kk)
                #pragma unroll
                for (int mi = 0; mi < 2; ++mi)
                    #pragma unroll
                    for (int nf = 0; nf < 2; ++nf)
                        acc[q * 2 + mi][nf] = __builtin_amdgcn_mfma_i32_16x16x64_i8(
                            afr[kk][mi], bfr[kk][nf], acc[q * 2 + mi][nf], 0, 0, 0);
            __builtin_amdgcn_s_setprio(0);
            if (q < 3) __builtin_amdgcn_s_barrier();
        }
        // End of K-tile: tile kt+1 must be fully landed before next iteration
        // reads it. Outstanding = 6 (tile kt+2, just issued) + remainder of
        // tile kt+1 -> vmcnt(6). The asm memory clobber also pins this
        // iteration's ds_reads above the trailing barrier (overwrite hazard).
        if (kt < 14)       asm volatile("s_waitcnt vmcnt(6)" ::: "memory");
        else if (kt == 14) asm volatile("s_waitcnt vmcnt(0)" ::: "memory");
        if (kt < 15) __builtin_amdgcn_s_barrier();
        sA += 49152; if (sA == 147456) sA = 0;
        sN += 49152; if (sN == 147456) sN = 0;
    }

#undef LDA
#undef LDB

    // Epilogue: four 64-row quarters through an LDS C-tile (aliases staging).
    // Quarter qr covers rows m0 + qr*64 + [0,64): wm = qr>>1, mf = (qr&1)*4 ..+4.
    float (*Cs)[132] = (float(*)[132])raw;   // [64][132] f32 = 33792 B
    const float sc = 0.0009765625f;          // 2^-10
    for (int qr = 0; qr < 4; ++qr) {
        __syncthreads();
        if (wm == (qr >> 1)) {
            const int mfb = (qr & 1) * 4;
            #pragma unroll
            for (int mf2 = 0; mf2 < 4; ++mf2) {
                const int rb = mf2 * 16 + ((l >> 4) << 2);
                #pragma unroll
                for (int nf = 0; nf < 2; ++nf) {
                    const int col = wn * 32 + nf * 16 + (l & 15);
                    #pragma unroll
                    for (int rr = 0; rr < 4; ++rr)
                        Cs[rb + rr][col] = (float)acc[mfb + mf2][nf][rr] * sc;
                }
            }
        }
        __syncthreads();
        #pragma unroll
        for (int it = 0; it < 4; ++it) {
            const int idx = it * 512 + t;        // 0..2047 = 64 rows x 32 j
            const int row = idx >> 5;
            const int jl = idx & 31;
            float4 y = *(const float4*)&Cs[row][jl << 2];
            float4 bv = *(const float4*)&bqp[n0 + (jl << 2)];
            const int m = m0 + qr * 64 + row;
            const int j = (n0 >> 2) + jl;
            const float ig = fqf(fsigm(y.x + bv.x));
            const float fg = fqf(fsigm(y.y + bv.y));
            const float gg = fqf(ftanh(y.z + bv.z));
            const float og = fqf(fsigm(y.w + bv.w));
            const float cq = fqf(cin[(size_t)m * 1024 + j]);
            const float cn = cq * fg + ig * gg;
            const float hn = fqf(ftanh(cn)) * og;
            hout[(size_t)m * 1024 + j] = hn;
            cout_[(size_t)m * 1024 + j] = cn;
        }
    }
}

extern "C" void kernel_launch(void* const* d_in, const int* in_sizes, int n_in,
                              void* d_out, int out_size, void* d_ws, size_t ws_size,
                              hipStream_t stream) {
    const float* X    = (const float*)d_in[0];   // [2048,1024]
    const float* h    = (const float*)d_in[1];   // [2048,1024]
    const float* c    = (const float*)d_in[2];   // [2048,1024]
    const float* W    = (const float*)d_in[3];   // [4096,2048]
    const float* bias = (const float*)d_in[4];   // [4096]

    float* out   = (float*)d_out;
    float* h_out = out;                          // [2048,1024]
    float* c_out = out + (size_t)B_DIM * 1024;   // [2048,1024]

    char* ws = (char*)d_ws;
    int8_t* Xhq = (int8_t*)ws;                              // 4 MB
    int8_t* Wq  = (int8_t*)(ws + (size_t)4 * 1024 * 1024);  // 8 MB
    float*  bqp = (float*)(ws + (size_t)12 * 1024 * 1024);  // 16 KB

    quant_pack<<<B_DIM + N_PACK + 1, 256, 0, stream>>>(X, h, W, bias, Xhq, Wq, bqp);

    lstm_gemm<<<256, 512, 0, stream>>>(Xhq, Wq, bqp, c, h_out, c_out);
}